// Round 7
// baseline (492.171 us; speedup 1.0000x reference)
//
#include <hip/hip_runtime.h>
#include <math.h>

#define NELEM   262144            // 4*64*32*32
#define NPAIRW  18432             // 64 o * 32 pairs * 9
#define PIMG    1296              // 36*36 padded image stride per (b,pair)
#define PPADN   165888            // 4*32*36*36 words
#define NPAIR   147968            // 4*32*34*34
#define EPS_BN  1e-5f
#define QSC     128.0f
#define QBIAS_F 16384.5f          // bias 16384 + 0.5 rounding
#define QZ_W    0x40004000u       // packed quantized zero
#define QINV    (1.0f / 128.0f)
#define GRID    1024

__device__ __forceinline__ unsigned sad16(unsigned a, unsigned b, unsigned acc) {
    asm("v_sad_u16 %0, %1, %2, %0" : "+v"(acc) : "v"(a), "v"(b));
    return acc;
}
__device__ __forceinline__ unsigned qu(float v) {
    return (unsigned)(int)fmaf(v, QSC, QBIAS_F);
}

// Grid-wide barrier: all 1024 blocks co-resident (guaranteed by
// __launch_bounds__(256,4): VGPR<=128, LDS ~20KB -> 4 blocks/CU x 256 CU).
// Release: threadfence (L2 writeback) before arrive; acquire: threadfence
// (L1/L2 inv) after spin. Counters zeroed by hipMemsetAsync each call.
__device__ __forceinline__ void grid_barrier(unsigned* bar) {
    __syncthreads();               // all waves' stores at vmcnt(0)
    if (threadIdx.x == 0) {
        __threadfence();           // device-scope release (wb L2)
        __hip_atomic_fetch_add(bar, 1u, __ATOMIC_RELEASE, __HIP_MEMORY_SCOPE_AGENT);
        while (__hip_atomic_load(bar, __ATOMIC_ACQUIRE, __HIP_MEMORY_SCOPE_AGENT) < GRID)
            __builtin_amdgcn_s_sleep(2);
        __threadfence();           // device-scope acquire (inv L1/L2)
    }
    __syncthreads();
}

// One adder pass on pair-packed u16 data (v_sad_u16: 2 terms/instr).
// PHASE=1: bn2+requant epilogue, u16 store into packed qout; returns 0.
// PHASE=2: returns final float value (kept in register by caller); SE
//          spatial-sum atomics into sbuf.
template<int PHASE>
__device__ __forceinline__ float adder_compute(
    const unsigned* __restrict__ qsrc, const unsigned* __restrict__ qwp,
    const float* __restrict__ bn2c, unsigned* __restrict__ qout,
    float* __restrict__ sbuf,
    unsigned (&wlds)[2][32][12], unsigned (&red)[16][16][16],
    int b, int og, int sp, int t)
{
    const int pos = t & 15;
    const int cq  = t >> 4;
    const int y_i = pos >> 2;
    const int x0  = (pos & 3) * 8;

    const unsigned* base = qsrc + (size_t)(b * 32 + cq * 2) * PIMG
                                + (sp * 4 + y_i) * 36 + x0;

    // issue pair-0 patch loads first (latency hides behind weight staging)
    unsigned p[2][3][12];
#pragma unroll
    for (int r = 0; r < 3; ++r) {
        uint4 a0 = *reinterpret_cast<const uint4*>(base + r * 36);
        uint4 a1 = *reinterpret_cast<const uint4*>(base + r * 36 + 4);
        uint4 a2 = *reinterpret_cast<const uint4*>(base + r * 36 + 8);
        p[0][r][0] = a0.x; p[0][r][1]  = a0.y; p[0][r][2]  = a0.z; p[0][r][3]  = a0.w;
        p[0][r][4] = a1.x; p[0][r][5]  = a1.y; p[0][r][6]  = a1.z; p[0][r][7]  = a1.w;
        p[0][r][8] = a2.x; p[0][r][9]  = a2.y; p[0][r][10] = a2.z; p[0][r][11] = a2.w;
    }

    for (int i = t; i < 576; i += 256) {
        int o_i = i / 288;
        int rem = i - o_i * 288;
        int pr  = rem / 9;
        int kk  = rem - pr * 9;
        wlds[o_i][pr][kk] = qwp[((og * 2 + o_i) * 32 + pr) * 9 + kk];
    }
    __syncthreads();

    unsigned acc[2][8];
#pragma unroll
    for (int oo = 0; oo < 2; ++oo)
#pragma unroll
        for (int xi = 0; xi < 8; ++xi) acc[oo][xi] = 0u;

#pragma unroll
    for (int j = 0; j < 2; ++j) {
        if (j == 0) {   // prefetch pair 1 before computing pair 0
            const unsigned* pn = base + PIMG;
#pragma unroll
            for (int r = 0; r < 3; ++r) {
                uint4 a0 = *reinterpret_cast<const uint4*>(pn + r * 36);
                uint4 a1 = *reinterpret_cast<const uint4*>(pn + r * 36 + 4);
                uint4 a2 = *reinterpret_cast<const uint4*>(pn + r * 36 + 8);
                p[1][r][0] = a0.x; p[1][r][1]  = a0.y; p[1][r][2]  = a0.z; p[1][r][3]  = a0.w;
                p[1][r][4] = a1.x; p[1][r][5]  = a1.y; p[1][r][6]  = a1.z; p[1][r][7]  = a1.w;
                p[1][r][8] = a2.x; p[1][r][9]  = a2.y; p[1][r][10] = a2.z; p[1][r][11] = a2.w;
            }
        }
        const int pr = cq * 2 + j;
#pragma unroll
        for (int oo = 0; oo < 2; ++oo) {
            uint4 wa = *reinterpret_cast<const uint4*>(&wlds[oo][pr][0]);
            uint4 wb = *reinterpret_cast<const uint4*>(&wlds[oo][pr][4]);
            unsigned w8 = wlds[oo][pr][8];
            unsigned wv[9] = {wa.x, wa.y, wa.z, wa.w,
                              wb.x, wb.y, wb.z, wb.w, w8};
#pragma unroll
            for (int kh = 0; kh < 3; ++kh)
#pragma unroll
                for (int kw = 0; kw < 3; ++kw) {
                    unsigned ww = wv[kh * 3 + kw];
#pragma unroll
                    for (int xi = 0; xi < 8; ++xi)
                        acc[oo][xi] = sad16(p[j][kh][xi + kw], ww, acc[oo][xi]);
                }
        }
    }

    {
        unsigned* dst = &red[cq][pos][0];
        *reinterpret_cast<uint4*>(dst + 0)  = make_uint4(acc[0][0], acc[0][1], acc[0][2], acc[0][3]);
        *reinterpret_cast<uint4*>(dst + 4)  = make_uint4(acc[0][4], acc[0][5], acc[0][6], acc[0][7]);
        *reinterpret_cast<uint4*>(dst + 8)  = make_uint4(acc[1][0], acc[1][1], acc[1][2], acc[1][3]);
        *reinterpret_cast<uint4*>(dst + 12) = make_uint4(acc[1][4], acc[1][5], acc[1][6], acc[1][7]);
    }
    __syncthreads();

    const int oo2 = t >> 7;
    const int s   = t & 127;
    const int yy2 = s >> 5;
    const int xx2 = s & 31;
    const int pp  = yy2 * 4 + (xx2 >> 3);
    const int z   = (oo2 << 3) | (xx2 & 7);
    unsigned total = 0;
#pragma unroll
    for (int q = 0; q < 16; ++q) total += red[q][pp][z];

    const int o    = og * 2 + oo2;
    const int gy   = sp * 4 + yy2;
    const float accf = (float)total;

    if (PHASE == 1) {
        float a2 = fmaxf(fmaf(accf, bn2c[o], bn2c[o + 64]), 0.f);
        unsigned short qv = (unsigned short)(int)fmaf(a2, QSC, QBIAS_F);
        size_t widx = (size_t)(b * 32 + (o >> 1)) * PIMG + (gy + 1) * 36 + (xx2 + 1);
        reinterpret_cast<unsigned short*>(qout)[widx * 2 + (o & 1)] = qv;
        return 0.f;
    } else {
        float v = -accf * QINV;
        float sum = v;          // wave-uniform o (waves 0,1 -> oo2=0; 2,3 -> 1)
#pragma unroll
        for (int off = 32; off > 0; off >>= 1)
            sum += __shfl_down(sum, off, 64);
        if ((t & 63) == 0) atomicAdd(&sbuf[b * 64 + o], sum);
        return v;
    }
}

// ---------------------------------------------------------------------------
// Single fused kernel: prep -> bar -> adder1 -> bar -> adder2 -> bar -> gate.
// Grid 1024 = b(4) x og(32) x sp(8); 256 threads.
// ---------------------------------------------------------------------------
__global__ __launch_bounds__(256, 4) void fused_kernel(
    const float* __restrict__ x,
    const float* __restrict__ g1, const float* __restrict__ b1,
    const float* __restrict__ m1, const float* __restrict__ v1,
    const float* __restrict__ w1,
    const float* __restrict__ g2, const float* __restrict__ b2,
    const float* __restrict__ m2, const float* __restrict__ v2,
    const float* __restrict__ w2,
    const float* __restrict__ fc1w, const float* __restrict__ fc1b,
    const float* __restrict__ fc2w, const float* __restrict__ fc2b,
    unsigned* __restrict__ qxp, unsigned* __restrict__ qout1p,
    unsigned* __restrict__ qw1p, unsigned* __restrict__ qw2p,
    float* __restrict__ bn2c, float* __restrict__ sbuf,
    unsigned* __restrict__ bars,
    float* __restrict__ out)
{
    __shared__ unsigned wlds[2][32][12];     // 3072 B
    __shared__ unsigned red[16][16][16];     // 16384 B
    __shared__ float ss[64];
    __shared__ float hh[4];

    const int blk = blockIdx.x;
    const int sp  = blk & 7;
    const int og  = (blk >> 3) & 31;
    const int b   = blk >> 8;
    const int t   = threadIdx.x;

    // ---- phase 0: prep (segmented flat index; 185,154 items < 262,144) ----
    {
        int i = blk * 256 + t;
        if (i < NPAIR) {
            int bp  = i / 1156;                       // b*32 + pair
            int rc  = i - bp * 1156;
            int r   = rc / 34;
            int col = rc - r * 34;
            bool interior = (r > 0 && r < 33 && col > 0 && col < 33);
            unsigned q = QZ_W;
            if (interior) {
                int bb = bp >> 5;
                int c0 = (bp & 31) * 2;
                float inv0 = g1[c0] * rsqrtf(v1[c0] + EPS_BN);
                float bet0 = b1[c0] - m1[c0] * inv0;
                float inv1 = g1[c0 + 1] * rsqrtf(v1[c0 + 1] + EPS_BN);
                float bet1 = b1[c0 + 1] - m1[c0 + 1] * inv1;
                int off = (bb * 64 + c0) * 1024 + (r - 1) * 32 + (col - 1);
                float a0 = fmaxf(fmaf(x[off],        inv0, bet0), 0.f);
                float a1 = fmaxf(fmaf(x[off + 1024], inv1, bet1), 0.f);
                q = qu(a0) | (qu(a1) << 16);
            }
            int pidx = bp * PIMG + r * 36 + col;
            qxp[pidx] = q;
            if (!interior) qout1p[pidx] = QZ_W;
        } else {
            int k = i - NPAIR;
            if (k < NPAIRW) {
                int o   = k / 288;
                int rem = k - o * 288;
                int pr  = rem / 9;
                int kk  = rem - pr * 9;
                int woff = (o * 64 + pr * 2) * 9 + kk;
                qw1p[k] = qu(w1[woff]) | (qu(w1[woff + 9]) << 16);
            } else {
                int l = k - NPAIRW;
                if (l < NPAIRW) {
                    int o   = l / 288;
                    int rem = l - o * 288;
                    int pr  = rem / 9;
                    int kk  = rem - pr * 9;
                    int woff = (o * 64 + pr * 2) * 9 + kk;
                    qw2p[l] = qu(w2[woff]) | (qu(w2[woff + 9]) << 16);
                } else {
                    int m = l - NPAIRW;
                    if (m < 64) {
                        float inv = g2[m] * rsqrtf(v2[m] + EPS_BN);
                        bn2c[m]      = -inv * QINV;
                        bn2c[m + 64] = b2[m] - m2[m] * inv;
                    } else {
                        int sfo = m - 64;
                        if (sfo >= 0 && sfo < 256) sbuf[sfo] = 0.f;
                    }
                }
            }
        }
    }
    grid_barrier(&bars[0]);

    // ---- phase 1: adder1 (qxp -> bn2+requant -> qout1p) ----
    adder_compute<1>(qxp, qw1p, bn2c, qout1p, sbuf, wlds, red, b, og, sp, t);
    grid_barrier(&bars[1]);

    // ---- phase 2: adder2 (qout1p -> v in register, SE sums) ----
    float v = adder_compute<2>(qout1p, qw2p, nullptr, nullptr, sbuf,
                               wlds, red, b, og, sp, t);
    grid_barrier(&bars[2]);

    // ---- phase 3: SE gate + shortcut, straight from registers ----
    if (t < 64) ss[t] = sbuf[b * 64 + t] * (1.f / 1024.f);
    __syncthreads();
    if (t < 64) {                        // wave 0 computes fc1 via shuffles
#pragma unroll
        for (int j = 0; j < 4; ++j) {
            float pr = ss[t] * fc1w[j * 64 + t];
#pragma unroll
            for (int off = 32; off > 0; off >>= 1)
                pr += __shfl_down(pr, off, 64);
            if (t == 0) hh[j] = fmaxf(pr + fc1b[j], 0.f);
        }
    }
    __syncthreads();

    const int oo2 = t >> 7;
    const int s   = t & 127;
    const int yy2 = s >> 5;
    const int xx2 = s & 31;
    const int o   = og * 2 + oo2;
    float zz = fc2b[o];
#pragma unroll
    for (int j = 0; j < 4; ++j) zz += hh[j] * fc2w[o * 4 + j];
    float g = 1.f / (1.f + __expf(-zz));

    const int idx = ((b * 64 + o) * 32 + sp * 4 + yy2) * 32 + xx2;
    out[idx] = fmaf(v, g, x[idx]);
}

// ---------------------------------------------------------------------------
extern "C" void kernel_launch(void* const* d_in, const int* in_sizes, int n_in,
                              void* d_out, int out_size, void* d_ws, size_t ws_size,
                              hipStream_t stream)
{
    const float* x    = (const float*)d_in[0];
    const float* bn1g = (const float*)d_in[1];
    const float* bn1b = (const float*)d_in[2];
    const float* bn1m = (const float*)d_in[3];
    const float* bn1v = (const float*)d_in[4];
    const float* w1   = (const float*)d_in[5];
    const float* bn2g = (const float*)d_in[6];
    const float* bn2b = (const float*)d_in[7];
    const float* bn2m = (const float*)d_in[8];
    const float* bn2v = (const float*)d_in[9];
    const float* w2   = (const float*)d_in[10];
    const float* fc1w = (const float*)d_in[11];
    const float* fc1b = (const float*)d_in[12];
    const float* fc2w = (const float*)d_in[13];
    const float* fc2b = (const float*)d_in[14];

    unsigned* ws     = (unsigned*)d_ws;
    unsigned* qxp    = ws;                              // PPADN
    unsigned* qout1p = ws + PPADN;                      // PPADN
    unsigned* qw1p   = ws + 2 * PPADN;                  // NPAIRW
    unsigned* qw2p   = ws + 2 * PPADN + NPAIRW;         // NPAIRW
    float*    bn2c   = (float*)(ws + 2 * PPADN + 2 * NPAIRW);        // 128
    float*    sbuf   = (float*)(ws + 2 * PPADN + 2 * NPAIRW + 128);  // 256
    unsigned* bars   = ws + 2 * PPADN + 2 * NPAIRW + 128 + 256;      // 3

    hipMemsetAsync(bars, 0, 3 * sizeof(unsigned), stream);
    fused_kernel<<<GRID, 256, 0, stream>>>(
        x, bn1g, bn1b, bn1m, bn1v, w1, bn2g, bn2b, bn2m, bn2v, w2,
        fc1w, fc1b, fc2w, fc2b,
        qxp, qout1p, qw1p, qw2p, bn2c, sbuf, bars, (float*)d_out);
}

// Round 8
// 117.256 us; speedup vs baseline: 4.1974x; 4.1974x over previous
//
#include <hip/hip_runtime.h>
#include <math.h>

#define NELEM   262144            // 4*64*32*32
#define PIMG    1296              // 36*36 padded image stride per (b,pair)
#define PPADN   165888            // 4*32*36*36 words
#define EPS_BN  1e-5f
#define QSC     128.0f
#define QBIAS_F 16384.5f          // bias 16384 + 0.5 rounding
#define QZ_W    0x40004000u       // packed quantized zero
#define QINV    (1.0f / 128.0f)

// v_sad_u16: acc += |a.lo-b.lo| + |a.hi-b.hi|  (two terms per instruction)
__device__ __forceinline__ unsigned sad16(unsigned a, unsigned b, unsigned acc) {
    asm("v_sad_u16 %0, %1, %2, %0" : "+v"(acc) : "v"(a), "v"(b));
    return acc;
}
__device__ __forceinline__ unsigned qu(float v) {
    return (unsigned)(int)fmaf(v, QSC, QBIAS_F);
}

// ---------------------------------------------------------------------------
// Kernel A: fused bn1+relu+quant staging (x -> LDS, no global qxp) + adder1 +
// bn2+requant epilogue -> padded pair-packed qout1p. og==0 blocks also write
// qout1p's halo; block 0 zeroes sbuf (safe: stream-ordered before kernel B).
// Grid 1024 = b(4) x og(32: 2 outputs) x sp(8: 4-row strips); 256 threads:
// pos=t&15 (y_i=pos>>2, x0=(pos&3)*8), cq=t>>4 -> 2 channel-pairs each.
// ---------------------------------------------------------------------------
__global__ __launch_bounds__(256, 4) void adder1_kernel(
    const float* __restrict__ x,
    const float* __restrict__ g1, const float* __restrict__ b1,
    const float* __restrict__ m1, const float* __restrict__ v1,
    const float* __restrict__ w1,
    const float* __restrict__ g2, const float* __restrict__ b2,
    const float* __restrict__ m2, const float* __restrict__ v2,
    unsigned* __restrict__ qout, float* __restrict__ sbuf)
{
    __shared__ union {
        unsigned tile[32][6][36];    // 27648 B: pair-packed bn1(x) tile
        unsigned red[16][16][16];    // 16384 B: cq-reduction (after last read)
    } sh;
    __shared__ unsigned wlds[2][32][12];   // 3072 B
    __shared__ float binv[64], bbeta[64];  // 512 B     -> ~31.2 KB total

    const int blk = blockIdx.x;
    const int sp  = blk & 7;
    const int og  = (blk >> 3) & 31;
    const int b   = blk >> 8;
    const int t   = threadIdx.x;
    const int pos = t & 15;
    const int cq  = t >> 4;
    const int y_i = pos >> 2;
    const int x0  = (pos & 3) * 8;

    if (t < 64) {
        float inv = g1[t] * rsqrtf(v1[t] + EPS_BN);
        binv[t]  = inv;
        bbeta[t] = b1[t] - m1[t] * inv;
    }
    // weight quant+pack: 2 o x 32 pairs x 9 words
    for (int i = t; i < 576; i += 256) {
        int o_i = i / 288;
        int rem = i - o_i * 288;
        int pr  = rem / 9;
        int kk  = rem - pr * 9;
        int woff = ((og * 2 + o_i) * 64 + pr * 2) * 9 + kk;
        wlds[o_i][pr][kk] = qu(w1[woff]) | (qu(w1[woff + 9]) << 16);
    }
    // qout1p halo (132 border words per (b,pair) image), by og==0 blocks
    if (og == 0) {
        for (int i = sp * 256 + t; i < 32 * 132; i += 2048) {
            int pair = i / 132;
            int rem  = i - pair * 132;
            int row, col;
            if (rem < 34)       { row = 0;            col = rem;       }
            else if (rem < 68)  { row = 33;           col = rem - 34;  }
            else if (rem < 100) { row = rem - 68 + 1; col = 0;         }
            else                { row = rem - 100 + 1; col = 33;       }
            qout[(size_t)(b * 32 + pair) * PIMG + row * 36 + col] = QZ_W;
        }
    }
    if (blk == 0) sbuf[t] = 0.f;
    __syncthreads();

    // ---- stage tile: 32 pairs x 6 rows, fused bn1+relu+quant+pack ----
    for (int i = t; i < 192; i += 256) {
        int pair = i / 6;
        int row  = i - pair * 6;
        int gy   = sp * 4 - 1 + row;
        unsigned* dst = &sh.tile[pair][row][0];
        if (gy < 0 || gy > 31) {
            for (int col = 0; col < 34; ++col) dst[col] = QZ_W;
        } else {
            dst[0] = QZ_W; dst[33] = QZ_W;
            const int c0 = pair * 2;
            const float inv0 = binv[c0],     bet0 = bbeta[c0];
            const float inv1 = binv[c0 + 1], bet1 = bbeta[c0 + 1];
            const float* px = x + (size_t)((b * 64 + c0) * 32 + gy) * 32;
#pragma unroll
            for (int gx = 0; gx < 32; gx += 4) {
                float4 u0 = *reinterpret_cast<const float4*>(px + gx);
                float4 u1 = *reinterpret_cast<const float4*>(px + 1024 + gx);
                dst[1 + gx]     = qu(fmaxf(fmaf(u0.x, inv0, bet0), 0.f))
                                | (qu(fmaxf(fmaf(u1.x, inv1, bet1), 0.f)) << 16);
                dst[1 + gx + 1] = qu(fmaxf(fmaf(u0.y, inv0, bet0), 0.f))
                                | (qu(fmaxf(fmaf(u1.y, inv1, bet1), 0.f)) << 16);
                dst[1 + gx + 2] = qu(fmaxf(fmaf(u0.z, inv0, bet0), 0.f))
                                | (qu(fmaxf(fmaf(u1.z, inv1, bet1), 0.f)) << 16);
                dst[1 + gx + 3] = qu(fmaxf(fmaf(u0.w, inv0, bet0), 0.f))
                                | (qu(fmaxf(fmaf(u1.w, inv1, bet1), 0.f)) << 16);
            }
        }
    }
    __syncthreads();

    // ---- sad compute: 2 pairs/thread from LDS tile ----
    unsigned acc[2][8];
#pragma unroll
    for (int oo = 0; oo < 2; ++oo)
#pragma unroll
        for (int xi = 0; xi < 8; ++xi) acc[oo][xi] = 0u;

#pragma unroll
    for (int j = 0; j < 2; ++j) {
        const int pr = cq * 2 + j;
        unsigned p[3][12];
#pragma unroll
        for (int r = 0; r < 3; ++r) {
            uint4 a0 = *reinterpret_cast<const uint4*>(&sh.tile[pr][y_i + r][x0]);
            uint4 a1 = *reinterpret_cast<const uint4*>(&sh.tile[pr][y_i + r][x0 + 4]);
            uint4 a2 = *reinterpret_cast<const uint4*>(&sh.tile[pr][y_i + r][x0 + 8]);
            p[r][0] = a0.x; p[r][1]  = a0.y; p[r][2]  = a0.z; p[r][3]  = a0.w;
            p[r][4] = a1.x; p[r][5]  = a1.y; p[r][6]  = a1.z; p[r][7]  = a1.w;
            p[r][8] = a2.x; p[r][9]  = a2.y; p[r][10] = a2.z; p[r][11] = a2.w;
        }
#pragma unroll
        for (int oo = 0; oo < 2; ++oo) {
            uint4 wa = *reinterpret_cast<const uint4*>(&wlds[oo][pr][0]);
            uint4 wb = *reinterpret_cast<const uint4*>(&wlds[oo][pr][4]);
            unsigned w8 = wlds[oo][pr][8];
            unsigned wv[9] = {wa.x, wa.y, wa.z, wa.w,
                              wb.x, wb.y, wb.z, wb.w, w8};
#pragma unroll
            for (int kh = 0; kh < 3; ++kh)
#pragma unroll
                for (int kw = 0; kw < 3; ++kw) {
                    unsigned ww = wv[kh * 3 + kw];
#pragma unroll
                    for (int xi = 0; xi < 8; ++xi)
                        acc[oo][xi] = sad16(p[kh][xi + kw], ww, acc[oo][xi]);
                }
        }
    }

    // ---- cq reduction (red aliases tile; all tile reads are done) ----
    __syncthreads();
    {
        unsigned* dst = &sh.red[cq][pos][0];
        *reinterpret_cast<uint4*>(dst + 0)  = make_uint4(acc[0][0], acc[0][1], acc[0][2], acc[0][3]);
        *reinterpret_cast<uint4*>(dst + 4)  = make_uint4(acc[0][4], acc[0][5], acc[0][6], acc[0][7]);
        *reinterpret_cast<uint4*>(dst + 8)  = make_uint4(acc[1][0], acc[1][1], acc[1][2], acc[1][3]);
        *reinterpret_cast<uint4*>(dst + 12) = make_uint4(acc[1][4], acc[1][5], acc[1][6], acc[1][7]);
    }
    __syncthreads();

    const int oo2 = t >> 7;
    const int s   = t & 127;
    const int yy2 = s >> 5;
    const int xx2 = s & 31;
    const int pp  = yy2 * 4 + (xx2 >> 3);
    const int z   = (oo2 << 3) | (xx2 & 7);
    unsigned total = 0;
#pragma unroll
    for (int q = 0; q < 16; ++q) total += sh.red[q][pp][z];

    // bn2 + requant epilogue (o is wave-uniform -> scalar loads)
    const int o  = og * 2 + oo2;
    const int gy = sp * 4 + yy2;
    float inv2 = g2[o] * rsqrtf(v2[o] + EPS_BN);
    float bet2 = b2[o] - m2[o] * inv2;
    float a2 = fmaxf(fmaf((float)total, -inv2 * QINV, bet2), 0.f);
    unsigned short qv = (unsigned short)(int)fmaf(a2, QSC, QBIAS_F);
    size_t widx = (size_t)(b * 32 + (o >> 1)) * PIMG + (gy + 1) * 36 + (xx2 + 1);
    reinterpret_cast<unsigned short*>(qout)[widx * 2 + (o & 1)] = qv;
}

// ---------------------------------------------------------------------------
// Kernel B: adder2 on packed qout1p (global direct reads, double-buffered) +
// float out2 + SE spatial-sum atomics. Self-quantizes w2.
// ---------------------------------------------------------------------------
__global__ __launch_bounds__(256, 4) void adder2_kernel(
    const unsigned* __restrict__ qsrc, const float* __restrict__ w2,
    float* __restrict__ fout, float* __restrict__ sbuf)
{
    __shared__ unsigned wlds[2][32][12];     // 3072 B
    __shared__ unsigned red[16][16][16];     // 16384 B

    const int blk = blockIdx.x;
    const int sp  = blk & 7;
    const int og  = (blk >> 3) & 31;
    const int b   = blk >> 8;
    const int t   = threadIdx.x;
    const int pos = t & 15;
    const int cq  = t >> 4;
    const int y_i = pos >> 2;
    const int x0  = (pos & 3) * 8;

    const unsigned* base = qsrc + (size_t)(b * 32 + cq * 2) * PIMG
                                + (sp * 4 + y_i) * 36 + x0;

    // issue pair-0 patch loads first (latency hides behind weight staging)
    unsigned p[2][3][12];
#pragma unroll
    for (int r = 0; r < 3; ++r) {
        uint4 a0 = *reinterpret_cast<const uint4*>(base + r * 36);
        uint4 a1 = *reinterpret_cast<const uint4*>(base + r * 36 + 4);
        uint4 a2 = *reinterpret_cast<const uint4*>(base + r * 36 + 8);
        p[0][r][0] = a0.x; p[0][r][1]  = a0.y; p[0][r][2]  = a0.z; p[0][r][3]  = a0.w;
        p[0][r][4] = a1.x; p[0][r][5]  = a1.y; p[0][r][6]  = a1.z; p[0][r][7]  = a1.w;
        p[0][r][8] = a2.x; p[0][r][9]  = a2.y; p[0][r][10] = a2.z; p[0][r][11] = a2.w;
    }

    // weight quant+pack: 2 o x 32 pairs x 9 words
    for (int i = t; i < 576; i += 256) {
        int o_i = i / 288;
        int rem = i - o_i * 288;
        int pr  = rem / 9;
        int kk  = rem - pr * 9;
        int woff = ((og * 2 + o_i) * 64 + pr * 2) * 9 + kk;
        wlds[o_i][pr][kk] = qu(w2[woff]) | (qu(w2[woff + 9]) << 16);
    }
    __syncthreads();

    unsigned acc[2][8];
#pragma unroll
    for (int oo = 0; oo < 2; ++oo)
#pragma unroll
        for (int xi = 0; xi < 8; ++xi) acc[oo][xi] = 0u;

#pragma unroll
    for (int j = 0; j < 2; ++j) {
        if (j == 0) {   // prefetch pair 1 before computing pair 0
            const unsigned* pn = base + PIMG;
#pragma unroll
            for (int r = 0; r < 3; ++r) {
                uint4 a0 = *reinterpret_cast<const uint4*>(pn + r * 36);
                uint4 a1 = *reinterpret_cast<const uint4*>(pn + r * 36 + 4);
                uint4 a2 = *reinterpret_cast<const uint4*>(pn + r * 36 + 8);
                p[1][r][0] = a0.x; p[1][r][1]  = a0.y; p[1][r][2]  = a0.z; p[1][r][3]  = a0.w;
                p[1][r][4] = a1.x; p[1][r][5]  = a1.y; p[1][r][6]  = a1.z; p[1][r][7]  = a1.w;
                p[1][r][8] = a2.x; p[1][r][9]  = a2.y; p[1][r][10] = a2.z; p[1][r][11] = a2.w;
            }
        }
        const int pr = cq * 2 + j;
#pragma unroll
        for (int oo = 0; oo < 2; ++oo) {
            uint4 wa = *reinterpret_cast<const uint4*>(&wlds[oo][pr][0]);
            uint4 wb = *reinterpret_cast<const uint4*>(&wlds[oo][pr][4]);
            unsigned w8 = wlds[oo][pr][8];
            unsigned wv[9] = {wa.x, wa.y, wa.z, wa.w,
                              wb.x, wb.y, wb.z, wb.w, w8};
#pragma unroll
            for (int kh = 0; kh < 3; ++kh)
#pragma unroll
                for (int kw = 0; kw < 3; ++kw) {
                    unsigned ww = wv[kh * 3 + kw];
#pragma unroll
                    for (int xi = 0; xi < 8; ++xi)
                        acc[oo][xi] = sad16(p[j][kh][xi + kw], ww, acc[oo][xi]);
                }
        }
    }

    {
        unsigned* dst = &red[cq][pos][0];
        *reinterpret_cast<uint4*>(dst + 0)  = make_uint4(acc[0][0], acc[0][1], acc[0][2], acc[0][3]);
        *reinterpret_cast<uint4*>(dst + 4)  = make_uint4(acc[0][4], acc[0][5], acc[0][6], acc[0][7]);
        *reinterpret_cast<uint4*>(dst + 8)  = make_uint4(acc[1][0], acc[1][1], acc[1][2], acc[1][3]);
        *reinterpret_cast<uint4*>(dst + 12) = make_uint4(acc[1][4], acc[1][5], acc[1][6], acc[1][7]);
    }
    __syncthreads();

    const int oo2 = t >> 7;
    const int s   = t & 127;
    const int yy2 = s >> 5;
    const int xx2 = s & 31;
    const int pp  = yy2 * 4 + (xx2 >> 3);
    const int z   = (oo2 << 3) | (xx2 & 7);
    unsigned total = 0;
#pragma unroll
    for (int q = 0; q < 16; ++q) total += red[q][pp][z];

    const int o  = og * 2 + oo2;
    const int gy = sp * 4 + yy2;
    float v = -(float)total * QINV;
    fout[((b * 64 + o) * 32 + gy) * 32 + xx2] = v;
    float sum = v;              // o is wave-uniform
#pragma unroll
    for (int off = 32; off > 0; off >>= 1)
        sum += __shfl_down(sum, off, 64);
    if ((t & 63) == 0) atomicAdd(&sbuf[b * 64 + o], sum);
}

// ---------------------------------------------------------------------------
// Kernel C: SE gate + apply + shortcut. 256 blocks x 256 threads.
// ---------------------------------------------------------------------------
__global__ __launch_bounds__(256) void gate_kernel(
    const float* __restrict__ out2, const float* __restrict__ x,
    const float* __restrict__ sbuf,
    const float* __restrict__ fc1w, const float* __restrict__ fc1b,
    const float* __restrict__ fc2w, const float* __restrict__ fc2b,
    float* __restrict__ out)
{
    const int bo = blockIdx.x;
    const int b  = bo >> 6;
    const int o  = bo & 63;
    const int t  = threadIdx.x;

    __shared__ float ss[64];
    if (t < 64) ss[t] = sbuf[b * 64 + t] * (1.f / 1024.f);
    __syncthreads();

    float h[4];
#pragma unroll
    for (int j = 0; j < 4; ++j) {
        float a = fc1b[j];
#pragma unroll
        for (int c = 0; c < 64; ++c) a += ss[c] * fc1w[j * 64 + c];
        h[j] = fmaxf(a, 0.f);
    }
    float zz = fc2b[o];
#pragma unroll
    for (int j = 0; j < 4; ++j) zz += h[j] * fc2w[o * 4 + j];
    float g = 1.f / (1.f + __expf(-zz));

    const int base = bo * 1024 + t * 4;
    float4 v  = *reinterpret_cast<const float4*>(out2 + base);
    float4 xv = *reinterpret_cast<const float4*>(x + base);
    float4 r;
    r.x = v.x * g + xv.x;
    r.y = v.y * g + xv.y;
    r.z = v.z * g + xv.z;
    r.w = v.w * g + xv.w;
    *reinterpret_cast<float4*>(out + base) = r;
}

// ---------------------------------------------------------------------------
extern "C" void kernel_launch(void* const* d_in, const int* in_sizes, int n_in,
                              void* d_out, int out_size, void* d_ws, size_t ws_size,
                              hipStream_t stream)
{
    const float* x    = (const float*)d_in[0];
    const float* bn1g = (const float*)d_in[1];
    const float* bn1b = (const float*)d_in[2];
    const float* bn1m = (const float*)d_in[3];
    const float* bn1v = (const float*)d_in[4];
    const float* w1   = (const float*)d_in[5];
    const float* bn2g = (const float*)d_in[6];
    const float* bn2b = (const float*)d_in[7];
    const float* bn2m = (const float*)d_in[8];
    const float* bn2v = (const float*)d_in[9];
    const float* w2   = (const float*)d_in[10];
    const float* fc1w = (const float*)d_in[11];
    const float* fc1b = (const float*)d_in[12];
    const float* fc2w = (const float*)d_in[13];
    const float* fc2b = (const float*)d_in[14];

    unsigned* ws     = (unsigned*)d_ws;
    unsigned* qout1p = ws;                          // PPADN
    float*    out2   = (float*)(ws + PPADN);        // NELEM
    float*    sbuf   = (float*)(ws + PPADN + NELEM);// 256

    adder1_kernel<<<1024, 256, 0, stream>>>(x, bn1g, bn1b, bn1m, bn1v, w1,
                                            bn2g, bn2b, bn2m, bn2v,
                                            qout1p, sbuf);
    adder2_kernel<<<1024, 256, 0, stream>>>(qout1p, w2, out2, sbuf);
    gate_kernel<<<256, 256, 0, stream>>>(out2, x, sbuf, fc1w, fc1b, fc2w, fc2b,
                                         (float*)d_out);
}

// Round 9
// 109.234 us; speedup vs baseline: 4.5057x; 1.0734x over previous
//
#include <hip/hip_runtime.h>
#include <math.h>

#define NELEM   262144            // 4*64*32*32
#define NPAIRW  18432             // 64 o * 32 pairs * 9
#define PIMG    1296              // 36*36 padded image stride per (b,pair)
#define PPADN   165888            // 4*32*36*36 words
#define NPAIR   147968            // 4*32*34*34
#define EPS_BN  1e-5f
#define QSC     128.0f
#define QBIAS_F 16384.5f          // bias 16384 + 0.5 rounding
#define QZ_W    0x40004000u       // packed quantized zero
#define QINV    (1.0f / 128.0f)

// v_sad_u16: acc += |a.lo-b.lo| + |a.hi-b.hi|  (two terms per instruction)
__device__ __forceinline__ unsigned sad16(unsigned a, unsigned b, unsigned acc) {
    asm("v_sad_u16 %0, %1, %2, %0" : "+v"(acc) : "v"(a), "v"(b));
    return acc;
}
__device__ __forceinline__ unsigned qu(float v) {
    return (unsigned)(int)fmaf(v, QSC, QBIAS_F);
}

// ---------------------------------------------------------------------------
// prep: pair-packed quantized padded input qxp[4][32][36][36] (u16x2 words),
// qout1p halo words, pair-packed weights qw1p/qw2p, bn2 consts, sbuf zero.
// ---------------------------------------------------------------------------
__global__ __launch_bounds__(256) void prep_kernel(
    const float* __restrict__ x,
    const float* __restrict__ g1, const float* __restrict__ b1,
    const float* __restrict__ m1, const float* __restrict__ v1,
    const float* __restrict__ w1,
    const float* __restrict__ g2, const float* __restrict__ b2,
    const float* __restrict__ m2, const float* __restrict__ v2,
    const float* __restrict__ w2,
    unsigned* __restrict__ qxp, unsigned* __restrict__ qout1p,
    unsigned* __restrict__ qw1p, unsigned* __restrict__ qw2p,
    float* __restrict__ bn2c, float* __restrict__ sbuf)
{
    int i = blockIdx.x * 256 + threadIdx.x;
    if (i < NPAIR) {
        int bp  = i / 1156;                       // b*32 + pair
        int rc  = i - bp * 1156;
        int r   = rc / 34;
        int col = rc - r * 34;
        bool interior = (r > 0 && r < 33 && col > 0 && col < 33);
        unsigned q = QZ_W;
        if (interior) {
            int b  = bp >> 5;
            int c0 = (bp & 31) * 2;
            float inv0 = g1[c0] * rsqrtf(v1[c0] + EPS_BN);
            float bet0 = b1[c0] - m1[c0] * inv0;
            float inv1 = g1[c0 + 1] * rsqrtf(v1[c0 + 1] + EPS_BN);
            float bet1 = b1[c0 + 1] - m1[c0 + 1] * inv1;
            int off = (b * 64 + c0) * 1024 + (r - 1) * 32 + (col - 1);
            float a0 = fmaxf(fmaf(x[off],        inv0, bet0), 0.f);
            float a1 = fmaxf(fmaf(x[off + 1024], inv1, bet1), 0.f);
            q = qu(a0) | (qu(a1) << 16);
        }
        int pidx = bp * PIMG + r * 36 + col;
        qxp[pidx] = q;
        if (!interior) qout1p[pidx] = QZ_W;
        return;
    }
    int k = i - NPAIR;
    if (k < NPAIRW) {
        int o   = k / 288;
        int rem = k - o * 288;
        int pr  = rem / 9;
        int kk  = rem - pr * 9;
        int woff = (o * 64 + pr * 2) * 9 + kk;
        qw1p[k] = qu(w1[woff]) | (qu(w1[woff + 9]) << 16);
        return;
    }
    int l = k - NPAIRW;
    if (l < NPAIRW) {
        int o   = l / 288;
        int rem = l - o * 288;
        int pr  = rem / 9;
        int kk  = rem - pr * 9;
        int woff = (o * 64 + pr * 2) * 9 + kk;
        qw2p[l] = qu(w2[woff]) | (qu(w2[woff + 9]) << 16);
        return;
    }
    int m = l - NPAIRW;
    if (m < 64) {
        float inv = g2[m] * rsqrtf(v2[m] + EPS_BN);
        bn2c[m]      = -inv * QINV;               // maps u32 acc -> bn2 pre-act
        bn2c[m + 64] = b2[m] - m2[m] * inv;
        return;
    }
    int s = m - 64;
    if (s >= 0 && s < 256) sbuf[s] = 0.f;
}

// ---------------------------------------------------------------------------
// Adder2d on pair-packed u16 data (v_sad_u16). Fine-grained blocks:
// Grid 2048 = b(4) x og(32: 2 outputs) x sp(16: 2-row strips); 256 threads.
// pos = t&15: y_i = pos>>3 (0..1), x0 = (pos&7)*4 (4-wide); cq = t>>4 ->
// 2 channel-pairs each -> per-thread acc[2 o][4 x], patch p[3][6] per pair.
// MODE 0: writes quant(relu(bn2(-acc))) u16 half into packed qout.
// MODE 1: writes float out2 + SE spatial-sum atomics into sbuf.
// ---------------------------------------------------------------------------
template<int MODE>
__global__ __launch_bounds__(256, 8) void adder_kernel(
    const unsigned* __restrict__ qsrc, const unsigned* __restrict__ qwp,
    const float* __restrict__ bn2c,
    unsigned* __restrict__ qout, float* __restrict__ fout,
    float* __restrict__ sbuf)
{
    __shared__ unsigned wlds[2][32][12];     // 3072 B
    __shared__ unsigned red[16][16][8];      // 8192 B  -> 11.3 KB total

    const int blk = blockIdx.x;
    const int sp  = blk & 15;                // rows [sp*2, sp*2+2)
    const int og  = (blk >> 4) & 31;
    const int b   = blk >> 9;
    const int t   = threadIdx.x;
    const int pos = t & 15;
    const int cq  = t >> 4;
    const int y_i = pos >> 3;                // 0..1
    const int x0  = (pos & 7) * 4;           // 0..28

    const unsigned* base = qsrc + (size_t)(b * 32 + cq * 2) * PIMG
                                + (sp * 2 + y_i) * 36 + x0;

    // weight staging: 2 o x 32 pairs x 9 words (~2.25 words/thread)
    for (int i = t; i < 576; i += 256) {
        int o_i = i / 288;
        int rem = i - o_i * 288;
        int pr  = rem / 9;
        int kk  = rem - pr * 9;
        wlds[o_i][pr][kk] = qwp[((og * 2 + o_i) * 32 + pr) * 9 + kk];
    }
    __syncthreads();

    unsigned acc[2][4];
#pragma unroll
    for (int oo = 0; oo < 2; ++oo)
#pragma unroll
        for (int xi = 0; xi < 4; ++xi) acc[oo][xi] = 0u;

#pragma unroll
    for (int j = 0; j < 2; ++j) {
        const unsigned* pc = base + j * PIMG;
        unsigned p[3][6];                    // 6 words/row: x4 + x2 loads
#pragma unroll
        for (int r = 0; r < 3; ++r) {
            uint4 a0 = *reinterpret_cast<const uint4*>(pc + r * 36);
            uint2 a1 = *reinterpret_cast<const uint2*>(pc + r * 36 + 4);
            p[r][0] = a0.x; p[r][1] = a0.y; p[r][2] = a0.z; p[r][3] = a0.w;
            p[r][4] = a1.x; p[r][5] = a1.y;
        }
        const int pr = cq * 2 + j;
#pragma unroll
        for (int oo = 0; oo < 2; ++oo) {
            uint4 wa = *reinterpret_cast<const uint4*>(&wlds[oo][pr][0]);
            uint4 wb = *reinterpret_cast<const uint4*>(&wlds[oo][pr][4]);
            unsigned w8 = wlds[oo][pr][8];
            unsigned wv[9] = {wa.x, wa.y, wa.z, wa.w,
                              wb.x, wb.y, wb.z, wb.w, w8};
#pragma unroll
            for (int kh = 0; kh < 3; ++kh)
#pragma unroll
                for (int kw = 0; kw < 3; ++kw) {
                    unsigned ww = wv[kh * 3 + kw];
#pragma unroll
                    for (int xi = 0; xi < 4; ++xi)
                        acc[oo][xi] = sad16(p[kh][xi + kw], ww, acc[oo][xi]);
                }
        }
    }

    // ---- cq reduction via LDS ----
    {
        unsigned* dst = &red[cq][pos][0];
        *reinterpret_cast<uint4*>(dst)     = make_uint4(acc[0][0], acc[0][1], acc[0][2], acc[0][3]);
        *reinterpret_cast<uint4*>(dst + 4) = make_uint4(acc[1][0], acc[1][1], acc[1][2], acc[1][3]);
    }
    __syncthreads();

    if (t < 128) {                           // 128 outputs: 2 o x 2 rows x 32 cols
        const int oo2 = t >> 6;
        const int yy2 = (t >> 5) & 1;
        const int xx2 = t & 31;
        const int pp  = yy2 * 8 + (xx2 >> 2);
        const int z   = oo2 * 4 + (xx2 & 3);
        unsigned total = 0;
#pragma unroll
        for (int q = 0; q < 16; ++q) total += red[q][pp][z];

        const int o  = og * 2 + oo2;         // wave-uniform (wave 0 -> o even, wave 1 -> odd)
        const int gy = sp * 2 + yy2;

        if (MODE == 0) {
            float a2 = fmaxf(fmaf((float)total, bn2c[o], bn2c[o + 64]), 0.f);
            unsigned short qv = (unsigned short)(int)fmaf(a2, QSC, QBIAS_F);
            size_t widx = (size_t)(b * 32 + (o >> 1)) * PIMG + (gy + 1) * 36 + (xx2 + 1);
            reinterpret_cast<unsigned short*>(qout)[widx * 2 + (o & 1)] = qv;
        } else {
            float v = -(float)total * QINV;
            fout[((b * 64 + o) * 32 + gy) * 32 + xx2] = v;
            float sum = v;
#pragma unroll
            for (int off = 32; off > 0; off >>= 1)
                sum += __shfl_down(sum, off, 64);
            if ((t & 63) == 0) atomicAdd(&sbuf[b * 64 + o], sum);
        }
    }
}

// ---------------------------------------------------------------------------
// SE gate + apply + shortcut. 256 blocks (one per b,o image) x 256 threads.
// ---------------------------------------------------------------------------
__global__ __launch_bounds__(256) void gate_kernel(
    const float* __restrict__ out2, const float* __restrict__ x,
    const float* __restrict__ sbuf,
    const float* __restrict__ fc1w, const float* __restrict__ fc1b,
    const float* __restrict__ fc2w, const float* __restrict__ fc2b,
    float* __restrict__ out)
{
    const int bo = blockIdx.x;
    const int b  = bo >> 6;
    const int o  = bo & 63;
    const int t  = threadIdx.x;

    __shared__ float ss[64];
    if (t < 64) ss[t] = sbuf[b * 64 + t] * (1.f / 1024.f);
    __syncthreads();

    float h[4];
#pragma unroll
    for (int j = 0; j < 4; ++j) {
        float a = fc1b[j];
#pragma unroll
        for (int c = 0; c < 64; ++c) a += ss[c] * fc1w[j * 64 + c];
        h[j] = fmaxf(a, 0.f);
    }
    float zz = fc2b[o];
#pragma unroll
    for (int j = 0; j < 4; ++j) zz += h[j] * fc2w[o * 4 + j];
    float g = 1.f / (1.f + __expf(-zz));

    const int base = bo * 1024 + t * 4;
    float4 v  = *reinterpret_cast<const float4*>(out2 + base);
    float4 xv = *reinterpret_cast<const float4*>(x + base);
    float4 r;
    r.x = v.x * g + xv.x;
    r.y = v.y * g + xv.y;
    r.z = v.z * g + xv.z;
    r.w = v.w * g + xv.w;
    *reinterpret_cast<float4*>(out + base) = r;
}

// ---------------------------------------------------------------------------
extern "C" void kernel_launch(void* const* d_in, const int* in_sizes, int n_in,
                              void* d_out, int out_size, void* d_ws, size_t ws_size,
                              hipStream_t stream)
{
    const float* x    = (const float*)d_in[0];
    const float* bn1g = (const float*)d_in[1];
    const float* bn1b = (const float*)d_in[2];
    const float* bn1m = (const float*)d_in[3];
    const float* bn1v = (const float*)d_in[4];
    const float* w1   = (const float*)d_in[5];
    const float* bn2g = (const float*)d_in[6];
    const float* bn2b = (const float*)d_in[7];
    const float* bn2m = (const float*)d_in[8];
    const float* bn2v = (const float*)d_in[9];
    const float* w2   = (const float*)d_in[10];
    const float* fc1w = (const float*)d_in[11];
    const float* fc1b = (const float*)d_in[12];
    const float* fc2w = (const float*)d_in[13];
    const float* fc2b = (const float*)d_in[14];

    unsigned* ws     = (unsigned*)d_ws;
    unsigned* qxp    = ws;                              // PPADN
    unsigned* qout1p = ws + PPADN;                      // PPADN
    float*    out2   = (float*)(ws + 2 * PPADN);        // NELEM
    unsigned* qw1p   = ws + 2 * PPADN + NELEM;          // NPAIRW
    unsigned* qw2p   = ws + 2 * PPADN + NELEM + NPAIRW; // NPAIRW
    float*    bn2c   = (float*)(ws + 2 * PPADN + NELEM + 2 * NPAIRW);        // 128
    float*    sbuf   = (float*)(ws + 2 * PPADN + NELEM + 2 * NPAIRW + 128);  // 256

    // segments: NPAIR + NPAIRW + NPAIRW + 64 + 256 = 185,152 -> 724 blocks
    prep_kernel<<<724, 256, 0, stream>>>(x, bn1g, bn1b, bn1m, bn1v, w1,
                                         bn2g, bn2b, bn2m, bn2v, w2,
                                         qxp, qout1p, qw1p, qw2p, bn2c, sbuf);
    adder_kernel<0><<<2048, 256, 0, stream>>>(qxp,    qw1p, bn2c, qout1p, nullptr, nullptr);
    adder_kernel<1><<<2048, 256, 0, stream>>>(qout1p, qw2p, nullptr, nullptr, out2, sbuf);
    gate_kernel<<<256, 256, 0, stream>>>(out2, x, sbuf, fc1w, fc1b, fc2w, fc2b,
                                         (float*)d_out);
}